// Round 4
// baseline (336.060 us; speedup 1.0000x reference)
//
#include <hip/hip_runtime.h>
#include <stdint.h>

// ---------------------------------------------------------------------------
// SelfAttention: out[b,n,d] = ( softmax( (X^T Wk)(X^T Wq)^T / 32 ) (X^T Wv) )^T
// B=16, N=D=1024.  Five 1024^3 matmuls as gemm_bt
// (C[m,n] = sum_k A[m,k]*B[n,k], K contiguous in both operands).
//
// R2: XCD swizzle (lid%8=XCD) -> FETCH 154->33 MB (ideal).  CONFIRMED.
// R3: BK=64 + coalesced bf16 epilogue -> 336 us, GEMMs at ~m97 plateau.
// R4: 32x32x16 MFMA (2382 vs 2075 TF ubench; -18% MFMA cycles/step),
//     3 projection GEMMs merged into one 3072-block dispatch, all four
//     transposes in one launch.  8 dispatches -> 5.
// ---------------------------------------------------------------------------

typedef __bf16 bf16x8_t  __attribute__((ext_vector_type(8)));
typedef float  f32x16_t  __attribute__((ext_vector_type(16)));

typedef __attribute__((address_space(3))) uint32_t as3_u32;
typedef __attribute__((address_space(1))) uint32_t as1_u32;

__device__ __forceinline__ void async_copy16(const void* g, const void* l) {
  __builtin_amdgcn_global_load_lds((const as1_u32*)(uintptr_t)g,
                                   (as3_u32*)(uint32_t)(uintptr_t)l,
                                   16, 0, 0);
}

__device__ __forceinline__ uint16_t f2bf(float f) {  // RNE
  uint32_t x = __float_as_uint(f);
  return (uint16_t)((x + 0x7fffu + ((x >> 16) & 1u)) >> 16);
}
__device__ __forceinline__ float bf2f(uint16_t b) {
  return __uint_as_float(((uint32_t)b) << 16);
}

struct G3 {
  const uint16_t* A[3]; const uint16_t* B[3]; void* C[3];
  size_t sA[3], sB[3], sC[3]; float alpha[3];
};

// C[m,n] = alpha * sum_k A[m,k] * B[n,k].  NG sub-GEMMs of 1024 blocks each.
// Tiles: 128x128, BK=64, v_mfma_f32_32x32x16_bf16 (2x2 of 32x32 per wave).
// LDS tile: row pitch 128 B, 8 chunks of 16 B, slot cp holds k-chunk
// cp ^ (m&7)  (spreads bank access; 2-way alias = free).
template <bool OUT_F32, int NG>
__global__ __launch_bounds__(256, 4)
void gemm_bt(G3 ga, int K, int ldc)
{
  __shared__ __align__(16) char smem[33792];   // 32 KB tiles; 33 KB epilogue
  char* As = smem;          // 128 x 64 bf16 = 16384 B
  char* Bs = smem + 16384;

  const int lid = blockIdx.x;
  const int g   = (NG == 1) ? 0 : (lid >> 10);
  const int l   = lid & 1023;
  // ---- XCD-aware swizzle: lid%8 = XCD; 2 batches per XCD (1024%8==0 so
  // the per-1024-group mapping is unchanged when NG=3) ----
  const int xcd  = l & 7;
  const int slot = l >> 3;
  const int z    = (xcd << 1) | (slot >> 6);
  const int t64  = slot & 63;
  const int bm0  = (t64 >> 3) << 7;
  const int bn0  = (t64 & 7) << 7;

  const uint16_t* A = ga.A[g] + (size_t)z * ga.sA[g];
  const uint16_t* B = ga.B[g] + (size_t)z * ga.sB[g];
  const float alpha = ga.alpha[g];

  const int t    = threadIdx.x;
  const int lane = t & 63;
  const int w    = t >> 6;
  const int l32  = lane & 31;   // row within 32 (A/B m/n, C col)
  const int kh   = lane >> 5;   // k-half selector
  const int wm   = (w >> 1) << 6;
  const int wn   = (w & 1) << 6;

  f32x16_t acc[2][2];
#pragma unroll
  for (int i = 0; i < 2; i++)
#pragma unroll
    for (int j = 0; j < 2; j++)
#pragma unroll
      for (int r = 0; r < 16; r++) acc[i][j][r] = 0.f;

  for (int k0 = 0; k0 < K; k0 += 64) {
    // ---- stage A,B 128x64 tiles (16 B/lane, 4 issues per operand) ----
#pragma unroll
    for (int i = 0; i < 4; i++) {
      const int o  = (i << 12) + (t << 4);
      const int m  = o >> 7;            // tile row (128 B rows)
      const int cp = (o >> 4) & 7;      // LDS chunk slot
      const int c  = cp ^ (m & 7);      // logical k-chunk held there
      async_copy16(A + (size_t)(bm0 + m) * K + (size_t)(k0 + (c << 3)), As + o);
      async_copy16(B + (size_t)(bn0 + m) * K + (size_t)(k0 + (c << 3)), Bs + o);
    }
    __syncthreads();

    // ---- four 16-k steps.  A frag: A[m=l32][k = kh*8 + j] ----
#pragma unroll
    for (int s = 0; s < 4; s++) {
      const int cidx = (s << 1) | kh;
      bf16x8_t af[2], bfr[2];
#pragma unroll
      for (int mi = 0; mi < 2; mi++) {
        const int m = wm + (mi << 5) + l32;
        af[mi] = *(const bf16x8_t*)(As + (m << 7) + ((cidx ^ (m & 7)) << 4));
      }
#pragma unroll
      for (int ni = 0; ni < 2; ni++) {
        const int n = wn + (ni << 5) + l32;
        bfr[ni] = *(const bf16x8_t*)(Bs + (n << 7) + ((cidx ^ (n & 7)) << 4));
      }
#pragma unroll
      for (int mi = 0; mi < 2; mi++)
#pragma unroll
        for (int ni = 0; ni < 2; ni++)
          acc[mi][ni] = __builtin_amdgcn_mfma_f32_32x32x16_bf16(
              af[mi], bfr[ni], acc[mi][ni], 0, 0, 0);
    }
    __syncthreads();
  }

  // ---- epilogue.  C/D: col=lane&31, row=(r&3)+8*(r>>2)+4*kh (m74/m101) ----
  if (OUT_F32) {
    float* C = (float*)ga.C[g] + (size_t)z * ga.sC[g];
#pragma unroll
    for (int mi = 0; mi < 2; mi++)
#pragma unroll
      for (int ni = 0; ni < 2; ni++)
#pragma unroll
        for (int r = 0; r < 16; r++) {
          const int row = bm0 + wm + (mi << 5) + (r & 3) + ((r >> 2) << 3) + (kh << 2);
          const int col = bn0 + wn + (ni << 5) + l32;
          C[(size_t)row * ldc + col] = acc[mi][ni][r] * alpha;
        }
  } else {
    // Per-wave-private LDS staging (32 rows x 66-float pitch) -> full 128-B
    // row-segment dword stores.  Regions private; K-loop's final barrier
    // already fenced smem.
    float* reg = (float*)smem + (size_t)w * (32 * 66);
    uint16_t* C = (uint16_t*)ga.C[g] + (size_t)z * ga.sC[g];
#pragma unroll
    for (int mi = 0; mi < 2; mi++) {
#pragma unroll
      for (int ni = 0; ni < 2; ni++)
#pragma unroll
        for (int r = 0; r < 16; r++) {
          const int row32 = (r & 3) + ((r >> 2) << 3) + (kh << 2);
          reg[row32 * 66 + (ni << 5) + l32] = acc[mi][ni][r] * alpha;
        }
#pragma unroll
      for (int it = 0; it < 16; it++) {
        const int rr = (it << 1) | kh;            // 0..31
        const int cc = l32 << 1;                  // 0..62
        const float2 v = *(const float2*)(reg + rr * 66 + cc);
        const uint32_t p = (uint32_t)f2bf(v.x) | ((uint32_t)f2bf(v.y) << 16);
        const int row = bm0 + wm + (mi << 5) + rr;
        const int col = bn0 + wn + cc;
        *(uint32_t*)(C + (size_t)row * ldc + col) = p;
      }
    }
  }
}

// All transposes in one launch: z<16 -> x batch z; z=16/17/18 -> wk/wq/wv.
// dst[c][r] = (bf16) src[r][c]; 1024x1024 fp32 row-major each.
__global__ __launch_bounds__(256)
void transpose_cast_all(const float* __restrict__ x,
                        const float* __restrict__ wk,
                        const float* __restrict__ wq,
                        const float* __restrict__ wv,
                        uint16_t* __restrict__ xT, uint16_t* __restrict__ Wtk,
                        uint16_t* __restrict__ Wtq, uint16_t* __restrict__ Wtv)
{
  __shared__ float tile[32][33];
  const int z = blockIdx.z;
  const float* src;
  uint16_t* dst;
  if (z < 16)      { src = x + (size_t)z * 1048576; dst = xT + (size_t)z * 1048576; }
  else if (z == 16){ src = wk; dst = Wtk; }
  else if (z == 17){ src = wq; dst = Wtq; }
  else             { src = wv; dst = Wtv; }
  const int c0 = blockIdx.x << 5;
  const int r0 = blockIdx.y << 5;
  const int tx = threadIdx.x;
  const int ty = threadIdx.y;
#pragma unroll
  for (int i = 0; i < 32; i += 8)
    tile[ty + i][tx] = src[(size_t)(r0 + ty + i) * 1024 + (c0 + tx)];
  __syncthreads();
#pragma unroll
  for (int i = 0; i < 32; i += 8)
    dst[(size_t)(c0 + ty + i) * 1024 + (r0 + tx)] = f2bf(tile[tx][ty + i]);
}

// row softmax over 1024 bf16 logits; one 256-thread block per row.
__global__ __launch_bounds__(256)
void softmax_rows(const uint16_t* __restrict__ in, uint16_t* __restrict__ out)
{
  const size_t row = blockIdx.x;
  const ushort4* p4 = (const ushort4*)(in + row * 1024);
  ushort4* o4 = (ushort4*)(out + row * 1024);
  const int t = threadIdx.x;
  const int lane = t & 63;
  const int wv = t >> 6;

  const ushort4 u = p4[t];
  float v0 = bf2f(u.x), v1 = bf2f(u.y), v2 = bf2f(u.z), v3 = bf2f(u.w);

  float m = fmaxf(fmaxf(v0, v1), fmaxf(v2, v3));
#pragma unroll
  for (int s = 32; s; s >>= 1) m = fmaxf(m, __shfl_xor(m, s, 64));
  __shared__ float red[8];
  if (lane == 0) red[wv] = m;
  __syncthreads();
  m = fmaxf(fmaxf(red[0], red[1]), fmaxf(red[2], red[3]));

  const float e0 = __expf(v0 - m), e1 = __expf(v1 - m);
  const float e2 = __expf(v2 - m), e3 = __expf(v3 - m);
  float s = e0 + e1 + e2 + e3;
#pragma unroll
  for (int sh = 32; sh; sh >>= 1) s += __shfl_xor(s, sh, 64);
  if (lane == 0) red[4 + wv] = s;
  __syncthreads();
  s = red[4] + red[5] + red[6] + red[7];

  const float inv = 1.0f / s;
  ushort4 r;
  r.x = f2bf(e0 * inv); r.y = f2bf(e1 * inv);
  r.z = f2bf(e2 * inv); r.w = f2bf(e3 * inv);
  o4[t] = r;
}

extern "C" void kernel_launch(void* const* d_in, const int* in_sizes, int n_in,
                              void* d_out, int out_size, void* d_ws, size_t ws_size,
                              hipStream_t stream)
{
  const float* x  = (const float*)d_in[0];
  const float* wk = (const float*)d_in[1];
  const float* wq = (const float*)d_in[2];
  const float* wv = (const float*)d_in[3];
  float* out = (float*)d_out;

  constexpr int BB = 16;
  constexpr size_t DN = 1048576;  // 1024*1024

  // workspace layout (bytes)            size    lifetime
  // xT   @ 0                            32 MB   dead after proj -> reused as kq
  // Wtk  @ 32M, Wtq @ 34M, Wtv @ 36M     6 MB
  // vk   @ 38M                          32 MB   dead after kq -> reused as sm
  // vq   @ 70M
  // vvT  @ 102M                         (total 134 MB)
  char* ws = (char*)d_ws;
  uint16_t* xT  = (uint16_t*)(ws);
  uint16_t* Wtk = (uint16_t*)(ws + (32ull << 20));
  uint16_t* Wtq = (uint16_t*)(ws + (34ull << 20));
  uint16_t* Wtv = (uint16_t*)(ws + (36ull << 20));
  uint16_t* vk  = (uint16_t*)(ws + (38ull << 20));
  uint16_t* vq  = (uint16_t*)(ws + (70ull << 20));
  uint16_t* vvT = (uint16_t*)(ws + (102ull << 20));
  uint16_t* kq  = xT;
  uint16_t* sm  = vk;

  transpose_cast_all<<<dim3(32, 32, 19), dim3(32, 8), 0, stream>>>(
      x, wk, wq, wv, xT, Wtk, Wtq, Wtv);

  // Projections (one dispatch, 3 x 1024 blocks):
  //   vk[b][d][k]  = sum_n xT[b][d][n]  * Wtk[k][n]
  //   vq[b][d][k]  = sum_n xT[b][d][n]  * Wtq[k][n]
  //   vvT[b][n][d] = sum_e Wtv[n][e]    * xT[b][d][e]
  G3 proj;
  proj.A[0] = xT;  proj.B[0] = Wtk; proj.C[0] = vk;
  proj.sA[0] = DN; proj.sB[0] = 0;  proj.sC[0] = DN; proj.alpha[0] = 1.0f;
  proj.A[1] = xT;  proj.B[1] = Wtq; proj.C[1] = vq;
  proj.sA[1] = DN; proj.sB[1] = 0;  proj.sC[1] = DN; proj.alpha[1] = 1.0f;
  proj.A[2] = Wtv; proj.B[2] = xT;  proj.C[2] = vvT;
  proj.sA[2] = 0;  proj.sB[2] = DN; proj.sC[2] = DN; proj.alpha[2] = 1.0f;
  gemm_bt<false, 3><<<3072, 256, 0, stream>>>(proj, 1024, 1024);

  // kq[b][d][e] = (1/32) sum_n vk[b][d][n] * vq[b][e][n]
  G3 gkq = {};
  gkq.A[0] = vk;  gkq.B[0] = vq; gkq.C[0] = kq;
  gkq.sA[0] = DN; gkq.sB[0] = DN; gkq.sC[0] = DN; gkq.alpha[0] = 0.03125f;
  gemm_bt<false, 1><<<1024, 256, 0, stream>>>(gkq, 1024, 1024);

  softmax_rows<<<BB * 1024, 256, 0, stream>>>(kq, sm);

  // out[b][n][d] = sum_e vvT[b][n][e] * sm[b][d][e]
  G3 gout = {};
  gout.A[0] = vvT; gout.B[0] = sm; gout.C[0] = out;
  gout.sA[0] = DN; gout.sB[0] = DN; gout.sC[0] = DN; gout.alpha[0] = 1.0f;
  gemm_bt<true, 1><<<1024, 256, 0, stream>>>(gout, 1024, 1024);
}